// Round 10
// baseline (262.425 us; speedup 1.0000x reference)
//
#include <hip/hip_runtime.h>
#include <math.h>

#define B_ 2
#define S_ 4096
#define D_ 1024
#define M_ 4
#define N_ (B_*S_)   // 8192 rows
#define EPS 1e-6f

typedef unsigned short u16;
typedef __bf16 bf16x8 __attribute__((ext_vector_type(8)));
typedef float  f32x4  __attribute__((ext_vector_type(4)));

__device__ __forceinline__ float elu1(float x) {
    // F.elu(x)+1 : x>0 -> x+1 ; x<=0 -> exp(x)
    return x > 0.0f ? x + 1.0f : __expf(x);
}

// fp32 -> bf16 round-to-nearest-even (finite inputs)
__device__ __forceinline__ u16 f2b(float f) {
    unsigned int u = __float_as_uint(f);
    return (u16)((u + 0x7FFFu + ((u >> 16) & 1u)) >> 16);
}

// async global->LDS, 16B per lane; LDS dest = wave-uniform base + lane*16
#define GLDS16(gp, lp) __builtin_amdgcn_global_load_lds( \
    (const __attribute__((address_space(1))) void*)(gp), \
    (__attribute__((address_space(3))) void*)(lp), 16, 0, 0)

// ---------------- per-row Q stats: qnorm[m,r] + sigma(Q) bf16.
// Blocks 0..31 also zero knorm (8192) / colsum (1024) — consumed only by the
// LATER prep_k kernel, so no ordering hazard.
__global__ __launch_bounds__(256) void k1_stats(
    const float* __restrict__ Q, const float* __restrict__ mnorm,
    float* __restrict__ qnorm,   // (M,N)
    u16* __restrict__ sQ,        // (N,D) bf16
    float* __restrict__ knorm, float* __restrict__ colsum)
{
    int r = blockIdx.x;
    int t = threadIdx.x;
    if (r < 32) {
        knorm[r * 256 + t] = 0.0f;
        if (r < 4) colsum[r * 256 + t] = 0.0f;
    }
    float4 q4 = *(const float4*)(Q + (size_t)r * D_ + t * 4);
    float sq0 = elu1(q4.x), sq1 = elu1(q4.y), sq2 = elu1(q4.z), sq3 = elu1(q4.w);

    uint2 sv;
    sv.x = (unsigned)f2b(sq0) | ((unsigned)f2b(sq1) << 16);
    sv.y = (unsigned)f2b(sq2) | ((unsigned)f2b(sq3) << 16);
    *(uint2*)(sQ + (size_t)r * D_ + t * 4) = sv;

    float vals[M_];
    #pragma unroll
    for (int m = 0; m < M_; ++m) {
        float4 w4 = *(const float4*)(mnorm + m * D_ + t * 4);
        vals[m] = sq0 * w4.x + sq1 * w4.y + sq2 * w4.z + sq3 * w4.w;
    }

    __shared__ float sbuf[M_][4];
    int wave = t >> 6, lane = t & 63;
    #pragma unroll
    for (int i = 0; i < M_; ++i) {
        float v = vals[i];
        #pragma unroll
        for (int off = 32; off > 0; off >>= 1) v += __shfl_down(v, off, 64);
        if (lane == 0) sbuf[i][wave] = v;
    }
    __syncthreads();
    if (t == 0) {
        #pragma unroll
        for (int m = 0; m < M_; ++m)
            qnorm[(size_t)m * N_ + r] = sbuf[m][0] + sbuf[m][1] + sbuf[m][2] + sbuf[m][3];
    }
}

// ---------------- sigma(K): bf16 row-major + bf16 transposed + colsum + knorm (one K pass)
__global__ __launch_bounds__(256) void prep_k(
    const float* __restrict__ K, const float* __restrict__ mnorm,
    u16* __restrict__ sk, u16* __restrict__ skT,
    float* __restrict__ colsum, float* __restrict__ knorm)
{
    __shared__ float tile[64][65];
    __shared__ float mn0[64];
    int r0 = blockIdx.x * 64;
    int d0 = blockIdx.y * 64;
    int t = threadIdx.x;
    int rr = t >> 4, c4 = (t & 15) * 4;
    if (t >= 128 && t < 192) mn0[t - 128] = mnorm[d0 + (t - 128)];
    #pragma unroll
    for (int i = 0; i < 4; ++i) {
        int rri = rr + i * 16;
        float4 k4 = *(const float4*)(K + (size_t)(r0 + rri) * D_ + d0 + c4);
        float e0 = elu1(k4.x), e1 = elu1(k4.y), e2 = elu1(k4.z), e3 = elu1(k4.w);
        uint2 v; v.x = (unsigned)f2b(e0) | ((unsigned)f2b(e1) << 16);
        v.y = (unsigned)f2b(e2) | ((unsigned)f2b(e3) << 16);
        *(uint2*)(sk + (size_t)(r0 + rri) * D_ + d0 + c4) = v;
        tile[rri][c4 + 0] = e0; tile[rri][c4 + 1] = e1;
        tile[rri][c4 + 2] = e2; tile[rri][c4 + 3] = e3;
    }
    __syncthreads();
    #pragma unroll
    for (int i = 0; i < 4; ++i) {
        int dd = rr + i * 16;
        float v0 = tile[c4 + 0][dd], v1 = tile[c4 + 1][dd];
        float v2 = tile[c4 + 2][dd], v3 = tile[c4 + 3][dd];
        uint2 v; v.x = (unsigned)f2b(v0) | ((unsigned)f2b(v1) << 16);
        v.y = (unsigned)f2b(v2) | ((unsigned)f2b(v3) << 16);
        *(uint2*)(skT + (size_t)(d0 + dd) * N_ + r0 + c4) = v;
    }
    if (t < 64) {               // wave 0: knorm partial dot with mnorm row 0
        float s = 0.0f;
        #pragma unroll
        for (int j = 0; j < 64; ++j) s += tile[t][j] * mn0[j];
        atomicAdd(&knorm[r0 + t], s);
    } else if (t < 128) {       // wave 1: column sums
        int c = t - 64;
        float s = 0.0f;
        #pragma unroll
        for (int j = 0; j < 64; ++j) s += tile[j][c];
        atomicAdd(&colsum[d0 + c], s);
    }
}

// ---------------- memories (4,1024,1024) -> MemT bf16 [e][m*1024+d].
// m==0 blocks also copy the raw fp32 Mem0 tile into out_mem.
__global__ __launch_bounds__(256) void prep_memT(
    const float* __restrict__ Mem, u16* __restrict__ MemT,
    float* __restrict__ out_mem)
{
    __shared__ float tile[64][65];
    int m = blockIdx.z;
    int e0 = blockIdx.x * 64, d0 = blockIdx.y * 64;
    int t = threadIdx.x, rr = t >> 4, c4 = (t & 15) * 4;
    #pragma unroll
    for (int i = 0; i < 4; ++i) {
        int dd = rr + i * 16;
        float4 v4 = *(const float4*)(Mem + ((size_t)m * D_ + d0 + dd) * D_ + e0 + c4);
        tile[dd][c4 + 0] = v4.x; tile[dd][c4 + 1] = v4.y;
        tile[dd][c4 + 2] = v4.z; tile[dd][c4 + 3] = v4.w;
        if (m == 0)
            *(float4*)(out_mem + (size_t)(d0 + dd) * D_ + e0 + c4) = v4;
    }
    __syncthreads();
    #pragma unroll
    for (int i = 0; i < 4; ++i) {
        int ee = rr + i * 16;
        float v0 = tile[c4 + 0][ee], v1 = tile[c4 + 1][ee];
        float v2 = tile[c4 + 2][ee], v3 = tile[c4 + 3][ee];
        uint2 v; v.x = (unsigned)f2b(v0) | ((unsigned)f2b(v1) << 16);
        v.y = (unsigned)f2b(v2) | ((unsigned)f2b(v3) << 16);
        *(uint2*)(MemT + (size_t)(e0 + ee) * (M_ * D_) + m * D_ + d0 + c4) = v;
    }
}

// ---------------- weights: |mnorm| reduce + relsum (from qnorm) + softmax over m
__global__ __launch_bounds__(512) void k2_weights(
    const float* __restrict__ mnorm, const float* __restrict__ qnorm,
    float* __restrict__ weights)
{
    __shared__ float sbuf[12][8];
    int t = threadIdx.x, wave = t >> 6, lane = t & 63;
    float vals[12];
    #pragma unroll
    for (int m = 0; m < M_; ++m) {
        float v = 0.0f;
        for (int d = t; d < D_; d += 512) v += fabsf(mnorm[m * D_ + d]);
        vals[m] = v;
    }
    #pragma unroll
    for (int mb = 0; mb < M_ * B_; ++mb) {
        int m = mb >> 1, b = mb & 1;
        const float4* p = (const float4*)(qnorm + (size_t)m * N_ + (size_t)b * S_);
        float v = 0.0f;
        for (int i = t; i < S_ / 4; i += 512) {
            float4 x = p[i];
            v += x.x + x.y + x.z + x.w;
        }
        vals[4 + mb] = v;
    }
    #pragma unroll
    for (int i = 0; i < 12; ++i) {
        float v = vals[i];
        #pragma unroll
        for (int off = 32; off > 0; off >>= 1) v += __shfl_down(v, off, 64);
        if (lane == 0) sbuf[i][wave] = v;
    }
    __syncthreads();
    if (t == 0) {
        bool empty[M_]; bool all_empty = true;
        float relsum[M_ * B_];
        #pragma unroll
        for (int m = 0; m < M_; ++m) {
            float sa = 0.0f;
            #pragma unroll
            for (int w = 0; w < 8; ++w) sa += sbuf[m][w];
            empty[m] = (sa < EPS);
            all_empty = all_empty && empty[m];
        }
        #pragma unroll
        for (int mb = 0; mb < M_ * B_; ++mb) {
            float sv = 0.0f;
            #pragma unroll
            for (int w = 0; w < 8; ++w) sv += sbuf[4 + mb][w];
            relsum[mb] = sv;
        }
        for (int b = 0; b < B_; ++b) {
            float rel[M_]; float mx = -3.0e38f;
            #pragma unroll
            for (int m = 0; m < M_; ++m) {
                rel[m] = empty[m] ? -1.0e30f : relsum[m * B_ + b] * (1.0f / (float)S_);
                mx = fmaxf(mx, rel[m]);
            }
            float se = 0.0f;
            #pragma unroll
            for (int m = 0; m < M_; ++m) { rel[m] = __expf(rel[m] - mx); se += rel[m]; }
            #pragma unroll
            for (int m = 0; m < M_; ++m) {
                float wv = rel[m] / se;
                if (empty[m] || all_empty) wv = 0.0f;
                weights[m * B_ + b] = wv;
            }
        }
    }
}

// ---------------- ratio planes for in-accumulator c-folding + new_memory_norm output
__global__ __launch_bounds__(256) void k2_cvec(
    const float* __restrict__ qnorm, const float* __restrict__ weights,
    const float* __restrict__ mnorm, const float* __restrict__ colsum,
    float* __restrict__ ratT, float* __restrict__ norm_out)
{
    int g = blockIdx.x * 256 + threadIdx.x;
    if (g < N_) {
        int b = g / S_;
        float cs[M_];
        #pragma unroll
        for (int m = 0; m < M_; ++m)
            cs[m] = fmaxf(weights[m * B_ + b] / fmaxf(qnorm[(size_t)m * N_ + g], EPS), 1e-20f);
        ratT[0 * (size_t)N_ + g] = cs[0] / cs[1];
        ratT[1 * (size_t)N_ + g] = cs[1] / cs[2];
        ratT[2 * (size_t)N_ + g] = cs[2] / cs[3];
        ratT[3 * (size_t)N_ + g] = cs[3];
    }
    if (g < D_) norm_out[g] = mnorm[g] + colsum[g] * (1.0f / (float)B_);
}

// ================= OLD 128²/4-wave 2-phase core (kept for g5_update) =================
__device__ __forceinline__ void tile_mma(
    const u16* Asb, const u16* Bsb, int aoff, int boff, f32x4 (&acc)[4][4])
{
    bf16x8 af[4], bf[4];
    #pragma unroll
    for (int i = 0; i < 4; ++i) {
        af[i] = *(const bf16x8*)((const char*)Asb + aoff + i * 1024);
        bf[i] = *(const bf16x8*)((const char*)Bsb + boff + i * 1024);
    }
    #pragma unroll
    for (int mi = 0; mi < 4; ++mi)
        #pragma unroll
        for (int ni = 0; ni < 4; ++ni)
            acc[mi][ni] = __builtin_amdgcn_mfma_f32_16x16x32_bf16(
                af[mi], bf[ni], acc[mi][ni], 0, 0, 0);
}

__device__ __forceinline__ void gemm_seg(
    u16* As, u16* Bs,   // each [2][4096] u16 in LDS
    const u16* __restrict__ A, int lda, int ak0,
    const u16* __restrict__ B, int ldb, int bk0,
    int rb, int cb, int klen,
    f32x4 (&acc)[4][4])
{
    const int tid  = threadIdx.x;
    const int lane = tid & 63;
    const int wid  = tid >> 6;
    const int wr   = wid >> 1, wc = wid & 1;
    const int r15  = lane & 15;

    const int srow0 = (wid * 2 + 0) * 16 + (lane >> 2);
    const int srow1 = (wid * 2 + 1) * 16 + (lane >> 2);
    const int sg    = ((lane & 3) ^ ((lane >> 3) & 3)) * 8;
    const u16* Ag0 = A + (size_t)(rb + srow0) * lda + ak0 + sg;
    const u16* Ag1 = A + (size_t)(rb + srow1) * lda + ak0 + sg;
    const u16* Bg0 = B + (size_t)(cb + srow0) * ldb + bk0 + sg;
    const u16* Bg1 = B + (size_t)(cb + srow1) * ldb + bk0 + sg;
    const int lo0 = (wid * 2 + 0) * 512;
    const int lo1 = (wid * 2 + 1) * 512;

    const int xo   = (((lane >> 4) ^ ((r15 >> 1) & 3)) * 16);
    const int aoff = (wr * 64 + r15) * 64 + xo;
    const int boff = (wc * 64 + r15) * 64 + xo;

    GLDS16(Ag0, As + lo0);
    GLDS16(Ag1, As + lo1);
    GLDS16(Bg0, Bs + lo0);
    GLDS16(Bg1, Bs + lo1);
    asm volatile("s_waitcnt vmcnt(0)" ::: "memory");
    __builtin_amdgcn_s_barrier();

    int cur = 0;
    for (int kt = 32; kt < klen; kt += 32) {
        int nxt = cur ^ 1;
        GLDS16(Ag0 + kt, As + nxt * 4096 + lo0);
        GLDS16(Ag1 + kt, As + nxt * 4096 + lo1);
        GLDS16(Bg0 + kt, Bs + nxt * 4096 + lo0);
        GLDS16(Bg1 + kt, Bs + nxt * 4096 + lo1);
        tile_mma(As + cur * 4096, Bs + cur * 4096, aoff, boff, acc);
        asm volatile("s_waitcnt vmcnt(0) lgkmcnt(0)" ::: "memory");
        __builtin_amdgcn_s_barrier();
        cur = nxt;
    }
    tile_mma(As + cur * 4096, Bs + cur * 4096, aoff, boff, acc);
    asm volatile("s_waitcnt lgkmcnt(0)" ::: "memory");
    __builtin_amdgcn_s_barrier();
}

// ================= NEW 256x128-tile / 8-wave / BK=64 core (g34) =================
// acc += A[rb..rb+256][k] * B[cb..cb+128][k]^T, k-contig bf16. 512 threads,
// 8 waves (4M x 2N), per wave 64x64 out = 4x4 frags of 16x16x32. 1 block/CU
// (96KB LDS). Same conservative sync as the proven 2-phase core, but 2x work
// per barrier + 2 waves/SIMD -> per-FLOP sync overhead halves (m233: that
// overhead is ~72% of the 2-phase step at 128²/4w).
// LDS row = 64k x 2B = 128B = 8 slots of 16B. XOR swizzle slot^=(row&7):
// frag reads (16 rows, fixed logical slot) spread over 8 banks-groups -> 2-way
// (free). glds writes linearly, so the GLOBAL source is pre-swizzled; since
// staging row%8 == lane>>3, the source slot ((lane&7)^(lane>>3)) is per-lane
// constant and pointers hoist out of the loop.
__device__ __forceinline__ void mma_tile8(
    const u16* Asb, const u16* Bsb, int arow, int brow,
    int s0, int s1, f32x4 (&acc)[4][4])
{
    bf16x8 af[4], bf[4];
    // kk = 0
    #pragma unroll
    for (int mi = 0; mi < 4; ++mi)
        af[mi] = *(const bf16x8*)((const char*)Asb + arow + mi * 2048 + s0);
    #pragma unroll
    for (int ni = 0; ni < 4; ++ni)
        bf[ni] = *(const bf16x8*)((const char*)Bsb + brow + ni * 2048 + s0);
    #pragma unroll
    for (int mi = 0; mi < 4; ++mi)
        #pragma unroll
        for (int ni = 0; ni < 4; ++ni)
            acc[mi][ni] = __builtin_amdgcn_mfma_f32_16x16x32_bf16(
                af[mi], bf[ni], acc[mi][ni], 0, 0, 0);
    // kk = 1
    #pragma unroll
    for (int mi = 0; mi < 4; ++mi)
        af[mi] = *(const bf16x8*)((const char*)Asb + arow + mi * 2048 + s1);
    #pragma unroll
    for (int ni = 0; ni < 4; ++ni)
        bf[ni] = *(const bf16x8*)((const char*)Bsb + brow + ni * 2048 + s1);
    #pragma unroll
    for (int mi = 0; mi < 4; ++mi)
        #pragma unroll
        for (int ni = 0; ni < 4; ++ni)
            acc[mi][ni] = __builtin_amdgcn_mfma_f32_16x16x32_bf16(
                af[mi], bf[ni], acc[mi][ni], 0, 0, 0);
}

__device__ __forceinline__ void gemm_seg8(
    u16* As, u16* Bs,   // As [2][16384] u16 (2x32KB), Bs [2][8192] u16 (2x16KB)
    const u16* __restrict__ A, int lda, int ak0,
    const u16* __restrict__ B, int ldb, int bk0,
    int rb, int cb, int klen,
    f32x4 (&acc)[4][4])
{
    const int tid  = threadIdx.x;
    const int lane = tid & 63;
    const int wid  = tid >> 6;
    const int wr   = wid >> 1, wc = wid & 1;
    const int r15  = lane & 15;

    // staging: round j covers LDS bytes [j*8KB + tid*16]; row = j*64 + (tid>>3),
    // phys slot = lane&7, logical (source) slot = (lane&7)^(row&7) = (lane&7)^(lane>>3)
    const int sg = (((lane & 7) ^ (lane >> 3)) * 8);   // elems
    const int rA = tid >> 3;                            // 0..63
    const u16* Ag0 = A + (size_t)(rb +   0 + rA) * lda + ak0 + sg;
    const u16* Ag1 = A + (size_t)(rb +  64 + rA) * lda + ak0 + sg;
    const u16* Ag2 = A + (size_t)(rb + 128 + rA) * lda + ak0 + sg;
    const u16* Ag3 = A + (size_t)(rb + 192 + rA) * lda + ak0 + sg;
    const u16* Bg0 = B + (size_t)(cb +   0 + rA) * ldb + bk0 + sg;
    const u16* Bg1 = B + (size_t)(cb +  64 + rA) * ldb + bk0 + sg;
    const int lw = wid * 512;   // wave base within an 8KB round (u16 units)

    // frag read offsets (bytes): row*128 + ((kk*4 + lane>>4) ^ (lane&7))*16
    const int arow = (wr * 64 + r15) * 128;
    const int brow = (wc * 64 + r15) * 128;
    const int g4 = lane >> 4, l7 = lane & 7;
    const int s0 = ((g4) ^ l7) * 16;
    const int s1 = ((4 + g4) ^ l7) * 16;

    // prologue: stage tile 0 into buffer 0 (6 glds/thread)
    GLDS16(Ag0, As + 0 * 4096 + lw);
    GLDS16(Ag1, As + 1 * 4096 + lw);
    GLDS16(Ag2, As + 2 * 4096 + lw);
    GLDS16(Ag3, As + 3 * 4096 + lw);
    GLDS16(Bg0, Bs + 0 * 4096 + lw);
    GLDS16(Bg1, Bs + 1 * 4096 + lw);
    asm volatile("s_waitcnt vmcnt(0)" ::: "memory");
    __builtin_amdgcn_s_barrier();

    int cur = 0;
    for (int kt = 64; kt < klen; kt += 64) {
        int nb = cur ^ 1;
        GLDS16(Ag0 + kt, As + nb * 16384 + 0 * 4096 + lw);
        GLDS16(Ag1 + kt, As + nb * 16384 + 1 * 4096 + lw);
        GLDS16(Ag2 + kt, As + nb * 16384 + 2 * 4096 + lw);
        GLDS16(Ag3 + kt, As + nb * 16384 + 3 * 4096 + lw);
        GLDS16(Bg0 + kt, Bs + nb * 8192 + 0 * 4096 + lw);
        GLDS16(Bg1 + kt, Bs + nb * 8192 + 1 * 4096 + lw);
        mma_tile8(As + cur * 16384, Bs + cur * 8192, arow, brow, s0, s1, acc);
        asm volatile("s_waitcnt vmcnt(0) lgkmcnt(0)" ::: "memory");
        __builtin_amdgcn_s_barrier();
        cur = nb;
    }
    mma_tile8(As + cur * 16384, Bs + cur * 8192, arow, brow, s0, s1, acc);
    // WAR fence for the NEXT segment's staging into these buffers
    asm volatile("s_waitcnt lgkmcnt(0)" ::: "memory");
    __builtin_amdgcn_s_barrier();
}

// ---------------- epilogues (formulas valid for both 4-wave and 8-wave grids)
__device__ __forceinline__ void epi_out(
    f32x4 (&acc)[4][4], float* __restrict__ out, int rb, int cb)
{
    int lane = threadIdx.x & 63, wid = threadIdx.x >> 6;
    int wr = wid >> 1, wc = wid & 1, r15 = lane & 15;
    #pragma unroll
    for (int mi = 0; mi < 4; ++mi) {
        int row0 = rb + wr * 64 + mi * 16 + (lane >> 4) * 4;
        #pragma unroll
        for (int ni = 0; ni < 4; ++ni) {
            int col = cb + wc * 64 + ni * 16 + r15;
            #pragma unroll
            for (int r = 0; r < 4; ++r)
                out[(size_t)(row0 + r) * D_ + col] = acc[mi][ni][r];
        }
    }
}

__device__ __forceinline__ void epi_delta(
    f32x4 (&acc)[4][4], const float* __restrict__ V,
    const float* __restrict__ knorm, u16* __restrict__ deltaT,
    int rb, int cb)
{
    int lane = threadIdx.x & 63, wid = threadIdx.x >> 6;
    int wr = wid >> 1, wc = wid & 1, r15 = lane & 15;
    #pragma unroll
    for (int mi = 0; mi < 4; ++mi) {
        int row0 = rb + wr * 64 + mi * 16 + (lane >> 4) * 4;
        float inv[4];
        #pragma unroll
        for (int r = 0; r < 4; ++r) inv[r] = 1.0f / fmaxf(knorm[row0 + r], EPS);
        #pragma unroll
        for (int ni = 0; ni < 4; ++ni) {
            int col = cb + wc * 64 + ni * 16 + r15;
            float dv[4];
            #pragma unroll
            for (int r = 0; r < 4; ++r)
                dv[r] = V[(size_t)(row0 + r) * D_ + col] - acc[mi][ni][r] * inv[r];
            uint2 pv;
            pv.x = (unsigned)f2b(dv[0]) | ((unsigned)f2b(dv[1]) << 16);
            pv.y = (unsigned)f2b(dv[2]) | ((unsigned)f2b(dv[3]) << 16);
            *(uint2*)(deltaT + (size_t)col * N_ + row0) = pv;  // lanes 0/16/32/48 coalesce
        }
    }
}

// ---------------- FUSED retrieve + delta, 256x128 tiles, 512 blocks @ 1 block/CU.
// Blocks [0,256): retrieve (32 row-tiles x 8 col-tiles; 4 K-segments with
// ratio-plane folding = 64 BK64-steps). Blocks [256,512): delta (16 steps).
// Retrieve-first order -> each CU runs one retrieve then one delta = 80 steps,
// the ideal makespan (old 128²/4-wave layout: 128). bx = hw&7 keeps one MemT
// panel per XCD.
__global__ __launch_bounds__(512, 2) void g34_fused(
    const u16* __restrict__ sQ, const u16* __restrict__ MemT,
    const u16* __restrict__ sk, const float* __restrict__ V,
    const float* __restrict__ knorm, const float* __restrict__ ratT,
    float* __restrict__ out, u16* __restrict__ deltaT)
{
    __shared__ u16 As[2 * 16384];   // 64 KB
    __shared__ u16 Bs[2 * 8192];    // 32 KB
    int hw = blockIdx.x;
    int lane = threadIdx.x & 63, wid = threadIdx.x >> 6;
    int wr = wid >> 1;
    f32x4 acc[4][4];
    #pragma unroll
    for (int i = 0; i < 4; ++i)
        #pragma unroll
        for (int j = 0; j < 4; ++j) {
            f32x4 zz = {0.0f, 0.0f, 0.0f, 0.0f};
            acc[i][j] = zz;
        }
    if (hw < 256) {
        int bx = hw & 7, by = hw >> 3;
        int rb = by * 256, cb = bx * 128;
        #pragma unroll 1
        for (int m = 0; m < M_; ++m) {
            gemm_seg8(As, Bs, sQ, D_, 0, MemT, M_ * D_, m * D_, rb, cb, D_, acc);
            const float* rp = ratT + (size_t)m * N_;
            #pragma unroll
            for (int mi = 0; mi < 4; ++mi) {
                int row0 = rb + wr * 64 + mi * 16 + (lane >> 4) * 4;
                float4 rt = *(const float4*)(rp + row0);
                #pragma unroll
                for (int ni = 0; ni < 4; ++ni) {
                    acc[mi][ni][0] *= rt.x; acc[mi][ni][1] *= rt.y;
                    acc[mi][ni][2] *= rt.z; acc[mi][ni][3] *= rt.w;
                }
            }
        }
        epi_out(acc, out, rb, cb);
    } else {
        int d = hw - 256;
        int bx = d & 7, by = d >> 3;
        int rb = by * 256, cb = bx * 128;
        gemm_seg8(As, Bs, sk, D_, 0, MemT, M_ * D_, 0, rb, cb, D_, acc);
        epi_delta(acc, V, knorm, deltaT, rb, cb);
    }
}

// ---------------- update: out_mem(D,D) += (skT * deltaT^T)/N, split-K=8, fp32 atomics
#define KSPLIT 8
__global__ __launch_bounds__(256, 4) void g5_update(
    const u16* __restrict__ skT, const u16* __restrict__ deltaT,
    float* __restrict__ memout)
{
    __shared__ u16 As[2 * 4096];
    __shared__ u16 Bs[2 * 4096];
    f32x4 acc[4][4];
    #pragma unroll
    for (int i = 0; i < 4; ++i)
        #pragma unroll
        for (int j = 0; j < 4; ++j) {
            f32x4 zz = {0.0f, 0.0f, 0.0f, 0.0f};
            acc[i][j] = zz;
        }
    int rb = blockIdx.y * 128, cb = blockIdx.x * 128;
    int k0 = blockIdx.z * (N_ / KSPLIT);
    gemm_seg(As, Bs, skT, N_, k0, deltaT, N_, k0, rb, cb, N_ / KSPLIT, acc);
    int lane = threadIdx.x & 63, wid = threadIdx.x >> 6;
    int wr = wid >> 1, wc = wid & 1, r15 = lane & 15;
    const float sc = 1.0f / (float)N_;
    #pragma unroll
    for (int mi = 0; mi < 4; ++mi) {
        int row0 = rb + wr * 64 + mi * 16 + (lane >> 4) * 4;
        #pragma unroll
        for (int ni = 0; ni < 4; ++ni) {
            int col = cb + wc * 64 + ni * 16 + r15;
            #pragma unroll
            for (int r = 0; r < 4; ++r)
                atomicAdd(memout + (size_t)(row0 + r) * D_ + col, acc[mi][ni][r] * sc);
        }
    }
}

extern "C" void kernel_launch(void* const* d_in, const int* in_sizes, int n_in,
                              void* d_out, int out_size, void* d_ws, size_t ws_size,
                              hipStream_t stream) {
    const float* Q     = (const float*)d_in[0];
    const float* K     = (const float*)d_in[1];
    const float* V     = (const float*)d_in[2];
    const float* Mem   = (const float*)d_in[3];
    const float* Mnorm = (const float*)d_in[4];

    float* out      = (float*)d_out;
    float* out_mem  = out + (size_t)N_ * D_;        // D*D
    float* out_norm = out_mem + (size_t)D_ * D_;    // D

    // ---- workspace layout (needs ~74MB; ws >= 121MB proven in prior rounds) ----
    // [0,1MB):   fp32 stats: qnorm(M*N) knorm(N) colsum(D) weights(8) ratT(4*N)
    // [1,9MB):   MemT  bf16 [1024][4096]
    // [9,25MB):  sk    bf16 [8192][1024]
    // [25,41MB): skT   bf16 [1024][8192]
    // [41,57MB): sQ    bf16 [8192][1024]
    // [57,73MB): deltaT bf16 [1024][8192]
    char* wsb = (char*)d_ws;
    float* qnorm   = (float*)wsb;                   // 32768
    float* knorm   = qnorm + (size_t)M_ * N_;       // 8192
    float* colsum  = knorm + N_;                    // 1024
    float* weights = colsum + D_;                   // 8
    float* ratT    = weights + M_ * B_;             // 4*N = 32768 (16B aligned)
    u16* MemT   = (u16*)(wsb + (size_t)1  * (1 << 20));
    u16* sk     = (u16*)(wsb + (size_t)9  * (1 << 20));
    u16* skT    = (u16*)(wsb + (size_t)25 * (1 << 20));
    u16* sQ     = (u16*)(wsb + (size_t)41 * (1 << 20));
    u16* deltaT = (u16*)(wsb + (size_t)57 * (1 << 20));

    hipLaunchKernelGGL(k1_stats, dim3(N_), dim3(256), 0, stream, Q, Mnorm, qnorm, sQ, knorm, colsum);
    hipLaunchKernelGGL(prep_k, dim3(128, 16), dim3(256), 0, stream, K, Mnorm, sk, skT, colsum, knorm);
    hipLaunchKernelGGL(prep_memT, dim3(16, 16, 4), dim3(256), 0, stream, Mem, MemT, out_mem);
    hipLaunchKernelGGL(k2_weights, dim3(1), dim3(512), 0, stream, Mnorm, qnorm, weights);
    hipLaunchKernelGGL(k2_cvec, dim3(32), dim3(256), 0, stream, qnorm, weights, Mnorm, colsum, ratT, out_norm);
    hipLaunchKernelGGL(g34_fused, dim3(512), dim3(512), 0, stream,
                       sQ, MemT, sk, V, knorm, ratT, out, deltaT);
    hipLaunchKernelGGL(g5_update, dim3(8, 8, KSPLIT), dim3(256), 0, stream, skT, deltaT, out_mem);
}

// Round 11
// 225.381 us; speedup vs baseline: 1.1644x; 1.1644x over previous
//
#include <hip/hip_runtime.h>
#include <math.h>

#define B_ 2
#define S_ 4096
#define D_ 1024
#define M_ 4
#define N_ (B_*S_)   // 8192 rows
#define EPS 1e-6f

typedef unsigned short u16;
typedef __bf16 bf16x8 __attribute__((ext_vector_type(8)));
typedef float  f32x4  __attribute__((ext_vector_type(4)));

__device__ __forceinline__ float elu1(float x) {
    // F.elu(x)+1 : x>0 -> x+1 ; x<=0 -> exp(x)
    return x > 0.0f ? x + 1.0f : __expf(x);
}

// fp32 -> bf16 round-to-nearest-even (finite inputs)
__device__ __forceinline__ u16 f2b(float f) {
    unsigned int u = __float_as_uint(f);
    return (u16)((u + 0x7FFFu + ((u >> 16) & 1u)) >> 16);
}

// async global->LDS, 16B per lane; LDS dest = wave-uniform base + lane*16
#define GLDS16(gp, lp) __builtin_amdgcn_global_load_lds( \
    (const __attribute__((address_space(1))) void*)(gp), \
    (__attribute__((address_space(3))) void*)(lp), 16, 0, 0)

// ---------------- per-row Q stats: qnorm[m,r] + sigma(Q) bf16.
// Blocks 0..31 also zero knorm (8192) / colsum (1024) — consumed only by the
// LATER prep_k kernel, so no ordering hazard.
__global__ __launch_bounds__(256) void k1_stats(
    const float* __restrict__ Q, const float* __restrict__ mnorm,
    float* __restrict__ qnorm,   // (M,N)
    u16* __restrict__ sQ,        // (N,D) bf16
    float* __restrict__ knorm, float* __restrict__ colsum)
{
    int r = blockIdx.x;
    int t = threadIdx.x;
    if (r < 32) {
        knorm[r * 256 + t] = 0.0f;
        if (r < 4) colsum[r * 256 + t] = 0.0f;
    }
    float4 q4 = *(const float4*)(Q + (size_t)r * D_ + t * 4);
    float sq0 = elu1(q4.x), sq1 = elu1(q4.y), sq2 = elu1(q4.z), sq3 = elu1(q4.w);

    uint2 sv;
    sv.x = (unsigned)f2b(sq0) | ((unsigned)f2b(sq1) << 16);
    sv.y = (unsigned)f2b(sq2) | ((unsigned)f2b(sq3) << 16);
    *(uint2*)(sQ + (size_t)r * D_ + t * 4) = sv;

    float vals[M_];
    #pragma unroll
    for (int m = 0; m < M_; ++m) {
        float4 w4 = *(const float4*)(mnorm + m * D_ + t * 4);
        vals[m] = sq0 * w4.x + sq1 * w4.y + sq2 * w4.z + sq3 * w4.w;
    }

    __shared__ float sbuf[M_][4];
    int wave = t >> 6, lane = t & 63;
    #pragma unroll
    for (int i = 0; i < M_; ++i) {
        float v = vals[i];
        #pragma unroll
        for (int off = 32; off > 0; off >>= 1) v += __shfl_down(v, off, 64);
        if (lane == 0) sbuf[i][wave] = v;
    }
    __syncthreads();
    if (t == 0) {
        #pragma unroll
        for (int m = 0; m < M_; ++m)
            qnorm[(size_t)m * N_ + r] = sbuf[m][0] + sbuf[m][1] + sbuf[m][2] + sbuf[m][3];
    }
}

// ---------------- sigma(K): bf16 row-major + bf16 transposed + colsum + knorm (one K pass)
__global__ __launch_bounds__(256) void prep_k(
    const float* __restrict__ K, const float* __restrict__ mnorm,
    u16* __restrict__ sk, u16* __restrict__ skT,
    float* __restrict__ colsum, float* __restrict__ knorm)
{
    __shared__ float tile[64][65];
    __shared__ float mn0[64];
    int r0 = blockIdx.x * 64;
    int d0 = blockIdx.y * 64;
    int t = threadIdx.x;
    int rr = t >> 4, c4 = (t & 15) * 4;
    if (t >= 128 && t < 192) mn0[t - 128] = mnorm[d0 + (t - 128)];
    #pragma unroll
    for (int i = 0; i < 4; ++i) {
        int rri = rr + i * 16;
        float4 k4 = *(const float4*)(K + (size_t)(r0 + rri) * D_ + d0 + c4);
        float e0 = elu1(k4.x), e1 = elu1(k4.y), e2 = elu1(k4.z), e3 = elu1(k4.w);
        uint2 v; v.x = (unsigned)f2b(e0) | ((unsigned)f2b(e1) << 16);
        v.y = (unsigned)f2b(e2) | ((unsigned)f2b(e3) << 16);
        *(uint2*)(sk + (size_t)(r0 + rri) * D_ + d0 + c4) = v;
        tile[rri][c4 + 0] = e0; tile[rri][c4 + 1] = e1;
        tile[rri][c4 + 2] = e2; tile[rri][c4 + 3] = e3;
    }
    __syncthreads();
    #pragma unroll
    for (int i = 0; i < 4; ++i) {
        int dd = rr + i * 16;
        float v0 = tile[c4 + 0][dd], v1 = tile[c4 + 1][dd];
        float v2 = tile[c4 + 2][dd], v3 = tile[c4 + 3][dd];
        uint2 v; v.x = (unsigned)f2b(v0) | ((unsigned)f2b(v1) << 16);
        v.y = (unsigned)f2b(v2) | ((unsigned)f2b(v3) << 16);
        *(uint2*)(skT + (size_t)(d0 + dd) * N_ + r0 + c4) = v;
    }
    if (t < 64) {               // wave 0: knorm partial dot with mnorm row 0
        float s = 0.0f;
        #pragma unroll
        for (int j = 0; j < 64; ++j) s += tile[t][j] * mn0[j];
        atomicAdd(&knorm[r0 + t], s);
    } else if (t < 128) {       // wave 1: column sums
        int c = t - 64;
        float s = 0.0f;
        #pragma unroll
        for (int j = 0; j < 64; ++j) s += tile[j][c];
        atomicAdd(&colsum[d0 + c], s);
    }
}

// ---------------- memories (4,1024,1024) -> MemT bf16 [e][m*1024+d].
// m==0 blocks also copy the raw fp32 Mem0 tile into out_mem.
__global__ __launch_bounds__(256) void prep_memT(
    const float* __restrict__ Mem, u16* __restrict__ MemT,
    float* __restrict__ out_mem)
{
    __shared__ float tile[64][65];
    int m = blockIdx.z;
    int e0 = blockIdx.x * 64, d0 = blockIdx.y * 64;
    int t = threadIdx.x, rr = t >> 4, c4 = (t & 15) * 4;
    #pragma unroll
    for (int i = 0; i < 4; ++i) {
        int dd = rr + i * 16;
        float4 v4 = *(const float4*)(Mem + ((size_t)m * D_ + d0 + dd) * D_ + e0 + c4);
        tile[dd][c4 + 0] = v4.x; tile[dd][c4 + 1] = v4.y;
        tile[dd][c4 + 2] = v4.z; tile[dd][c4 + 3] = v4.w;
        if (m == 0)
            *(float4*)(out_mem + (size_t)(d0 + dd) * D_ + e0 + c4) = v4;
    }
    __syncthreads();
    #pragma unroll
    for (int i = 0; i < 4; ++i) {
        int ee = rr + i * 16;
        float v0 = tile[c4 + 0][ee], v1 = tile[c4 + 1][ee];
        float v2 = tile[c4 + 2][ee], v3 = tile[c4 + 3][ee];
        uint2 v; v.x = (unsigned)f2b(v0) | ((unsigned)f2b(v1) << 16);
        v.y = (unsigned)f2b(v2) | ((unsigned)f2b(v3) << 16);
        *(uint2*)(MemT + (size_t)(e0 + ee) * (M_ * D_) + m * D_ + d0 + c4) = v;
    }
}

// ---------------- weights: |mnorm| reduce + relsum (from qnorm) + softmax over m
__global__ __launch_bounds__(512) void k2_weights(
    const float* __restrict__ mnorm, const float* __restrict__ qnorm,
    float* __restrict__ weights)
{
    __shared__ float sbuf[12][8];
    int t = threadIdx.x, wave = t >> 6, lane = t & 63;
    float vals[12];
    #pragma unroll
    for (int m = 0; m < M_; ++m) {
        float v = 0.0f;
        for (int d = t; d < D_; d += 512) v += fabsf(mnorm[m * D_ + d]);
        vals[m] = v;
    }
    #pragma unroll
    for (int mb = 0; mb < M_ * B_; ++mb) {
        int m = mb >> 1, b = mb & 1;
        const float4* p = (const float4*)(qnorm + (size_t)m * N_ + (size_t)b * S_);
        float v = 0.0f;
        for (int i = t; i < S_ / 4; i += 512) {
            float4 x = p[i];
            v += x.x + x.y + x.z + x.w;
        }
        vals[4 + mb] = v;
    }
    #pragma unroll
    for (int i = 0; i < 12; ++i) {
        float v = vals[i];
        #pragma unroll
        for (int off = 32; off > 0; off >>= 1) v += __shfl_down(v, off, 64);
        if (lane == 0) sbuf[i][wave] = v;
    }
    __syncthreads();
    if (t == 0) {
        bool empty[M_]; bool all_empty = true;
        float relsum[M_ * B_];
        #pragma unroll
        for (int m = 0; m < M_; ++m) {
            float sa = 0.0f;
            #pragma unroll
            for (int w = 0; w < 8; ++w) sa += sbuf[m][w];
            empty[m] = (sa < EPS);
            all_empty = all_empty && empty[m];
        }
        #pragma unroll
        for (int mb = 0; mb < M_ * B_; ++mb) {
            float sv = 0.0f;
            #pragma unroll
            for (int w = 0; w < 8; ++w) sv += sbuf[4 + mb][w];
            relsum[mb] = sv;
        }
        for (int b = 0; b < B_; ++b) {
            float rel[M_]; float mx = -3.0e38f;
            #pragma unroll
            for (int m = 0; m < M_; ++m) {
                rel[m] = empty[m] ? -1.0e30f : relsum[m * B_ + b] * (1.0f / (float)S_);
                mx = fmaxf(mx, rel[m]);
            }
            float se = 0.0f;
            #pragma unroll
            for (int m = 0; m < M_; ++m) { rel[m] = __expf(rel[m] - mx); se += rel[m]; }
            #pragma unroll
            for (int m = 0; m < M_; ++m) {
                float wv = rel[m] / se;
                if (empty[m] || all_empty) wv = 0.0f;
                weights[m * B_ + b] = wv;
            }
        }
    }
}

// ---------------- ratio planes for in-accumulator c-folding + new_memory_norm output
__global__ __launch_bounds__(256) void k2_cvec(
    const float* __restrict__ qnorm, const float* __restrict__ weights,
    const float* __restrict__ mnorm, const float* __restrict__ colsum,
    float* __restrict__ ratT, float* __restrict__ norm_out)
{
    int g = blockIdx.x * 256 + threadIdx.x;
    if (g < N_) {
        int b = g / S_;
        float cs[M_];
        #pragma unroll
        for (int m = 0; m < M_; ++m)
            cs[m] = fmaxf(weights[m * B_ + b] / fmaxf(qnorm[(size_t)m * N_ + g], EPS), 1e-20f);
        ratT[0 * (size_t)N_ + g] = cs[0] / cs[1];
        ratT[1 * (size_t)N_ + g] = cs[1] / cs[2];
        ratT[2 * (size_t)N_ + g] = cs[2] / cs[3];
        ratT[3 * (size_t)N_ + g] = cs[3];
    }
    if (g < D_) norm_out[g] = mnorm[g] + colsum[g] * (1.0f / (float)B_);
}

// ================= OLD 128²/4-wave 2-phase core (kept for g5_update) =================
__device__ __forceinline__ void tile_mma(
    const u16* Asb, const u16* Bsb, int aoff, int boff, f32x4 (&acc)[4][4])
{
    bf16x8 af[4], bf[4];
    #pragma unroll
    for (int i = 0; i < 4; ++i) {
        af[i] = *(const bf16x8*)((const char*)Asb + aoff + i * 1024);
        bf[i] = *(const bf16x8*)((const char*)Bsb + boff + i * 1024);
    }
    #pragma unroll
    for (int mi = 0; mi < 4; ++mi)
        #pragma unroll
        for (int ni = 0; ni < 4; ++ni)
            acc[mi][ni] = __builtin_amdgcn_mfma_f32_16x16x32_bf16(
                af[mi], bf[ni], acc[mi][ni], 0, 0, 0);
}

__device__ __forceinline__ void gemm_seg(
    u16* As, u16* Bs,   // each [2][4096] u16 in LDS
    const u16* __restrict__ A, int lda, int ak0,
    const u16* __restrict__ B, int ldb, int bk0,
    int rb, int cb, int klen,
    f32x4 (&acc)[4][4])
{
    const int tid  = threadIdx.x;
    const int lane = tid & 63;
    const int wid  = tid >> 6;
    const int wr   = wid >> 1, wc = wid & 1;
    const int r15  = lane & 15;

    const int srow0 = (wid * 2 + 0) * 16 + (lane >> 2);
    const int srow1 = (wid * 2 + 1) * 16 + (lane >> 2);
    const int sg    = ((lane & 3) ^ ((lane >> 3) & 3)) * 8;
    const u16* Ag0 = A + (size_t)(rb + srow0) * lda + ak0 + sg;
    const u16* Ag1 = A + (size_t)(rb + srow1) * lda + ak0 + sg;
    const u16* Bg0 = B + (size_t)(cb + srow0) * ldb + bk0 + sg;
    const u16* Bg1 = B + (size_t)(cb + srow1) * ldb + bk0 + sg;
    const int lo0 = (wid * 2 + 0) * 512;
    const int lo1 = (wid * 2 + 1) * 512;

    const int xo   = (((lane >> 4) ^ ((r15 >> 1) & 3)) * 16);
    const int aoff = (wr * 64 + r15) * 64 + xo;
    const int boff = (wc * 64 + r15) * 64 + xo;

    GLDS16(Ag0, As + lo0);
    GLDS16(Ag1, As + lo1);
    GLDS16(Bg0, Bs + lo0);
    GLDS16(Bg1, Bs + lo1);
    asm volatile("s_waitcnt vmcnt(0)" ::: "memory");
    __builtin_amdgcn_s_barrier();

    int cur = 0;
    for (int kt = 32; kt < klen; kt += 32) {
        int nxt = cur ^ 1;
        GLDS16(Ag0 + kt, As + nxt * 4096 + lo0);
        GLDS16(Ag1 + kt, As + nxt * 4096 + lo1);
        GLDS16(Bg0 + kt, Bs + nxt * 4096 + lo0);
        GLDS16(Bg1 + kt, Bs + nxt * 4096 + lo1);
        tile_mma(As + cur * 4096, Bs + cur * 4096, aoff, boff, acc);
        asm volatile("s_waitcnt vmcnt(0) lgkmcnt(0)" ::: "memory");
        __builtin_amdgcn_s_barrier();
        cur = nxt;
    }
    tile_mma(As + cur * 4096, Bs + cur * 4096, aoff, boff, acc);
    asm volatile("s_waitcnt lgkmcnt(0)" ::: "memory");
    __builtin_amdgcn_s_barrier();
}

// ================= 256x128-tile / 8-wave / BK=64 core, COUNTED-VMCNT depth-2 =================
// Geometry identical to R10 (correctness-verified there); only the sync schedule
// changes. THREE buffers per operand (A 3x32KB + B 3x16KB = 144KB LDS, 1 block/CU):
// tiles t, t+1, t+2 in flight. Per tile: wait vmcnt(6) (own 6 loads of tile t
// landed; t+1's 6 still flying) -> barrier -> issue stage(t+2) -> setprio(1) +
// 64 MFMA. Never vmcnt(0) in the loop (T4): issue-to-wait distance = 2 full
// iterations covers L3/HBM latency — replacing the inter-block TLP that 1
// block/CU lacks (R10's drain-0 at 1 block/CU stalled the whole CU each step).
// WAR safety: stage(t+2) targets buf[(t-1)%3]; all waves' ds_reads of t-1
// completed before they passed barrier(t) (MFMA register uses force lgkm
// completion pre-barrier), and glds is issued only post-barrier.
__device__ __forceinline__ void mma_tile8(
    const u16* Asb, const u16* Bsb, int arow, int brow,
    int s0, int s1, f32x4 (&acc)[4][4])
{
    bf16x8 af[4], bf[4];
    // kk = 0
    #pragma unroll
    for (int mi = 0; mi < 4; ++mi)
        af[mi] = *(const bf16x8*)((const char*)Asb + arow + mi * 2048 + s0);
    #pragma unroll
    for (int ni = 0; ni < 4; ++ni)
        bf[ni] = *(const bf16x8*)((const char*)Bsb + brow + ni * 2048 + s0);
    #pragma unroll
    for (int mi = 0; mi < 4; ++mi)
        #pragma unroll
        for (int ni = 0; ni < 4; ++ni)
            acc[mi][ni] = __builtin_amdgcn_mfma_f32_16x16x32_bf16(
                af[mi], bf[ni], acc[mi][ni], 0, 0, 0);
    // kk = 1
    #pragma unroll
    for (int mi = 0; mi < 4; ++mi)
        af[mi] = *(const bf16x8*)((const char*)Asb + arow + mi * 2048 + s1);
    #pragma unroll
    for (int ni = 0; ni < 4; ++ni)
        bf[ni] = *(const bf16x8*)((const char*)Bsb + brow + ni * 2048 + s1);
    #pragma unroll
    for (int mi = 0; mi < 4; ++mi)
        #pragma unroll
        for (int ni = 0; ni < 4; ++ni)
            acc[mi][ni] = __builtin_amdgcn_mfma_f32_16x16x32_bf16(
                af[mi], bf[ni], acc[mi][ni], 0, 0, 0);
}

__device__ __forceinline__ void gemm_seg8p(
    u16* As, u16* Bs,   // As [3][16384] u16 (3x32KB), Bs [3][8192] u16 (3x16KB)
    const u16* __restrict__ A, int lda, int ak0,
    const u16* __restrict__ B, int ldb, int bk0,
    int rb, int cb, int klen,
    f32x4 (&acc)[4][4])
{
    const int tid  = threadIdx.x;
    const int lane = tid & 63;
    const int wid  = tid >> 6;
    const int wr   = wid >> 1, wc = wid & 1;
    const int r15  = lane & 15;

    // staging (verified in R10): round j covers LDS bytes [j*8KB + tid*16];
    // row = j*64 + (tid>>3), phys slot = tid&7, source slot = phys ^ (row&7)
    // = (lane&7)^(lane>>3) — per-lane constant, pointers hoist.
    const int sg = (((lane & 7) ^ (lane >> 3)) * 8);   // elems
    const int rA = tid >> 3;                            // 0..63
    const u16* Ag0 = A + (size_t)(rb +   0 + rA) * lda + ak0 + sg;
    const u16* Ag1 = A + (size_t)(rb +  64 + rA) * lda + ak0 + sg;
    const u16* Ag2 = A + (size_t)(rb + 128 + rA) * lda + ak0 + sg;
    const u16* Ag3 = A + (size_t)(rb + 192 + rA) * lda + ak0 + sg;
    const u16* Bg0 = B + (size_t)(cb +   0 + rA) * ldb + bk0 + sg;
    const u16* Bg1 = B + (size_t)(cb +  64 + rA) * ldb + bk0 + sg;
    const int lw = wid * 512;   // wave base within an 8KB round (u16 units)

    // frag read offsets (bytes): row*128 + ((kk*4 + lane>>4) ^ (lane&7))*16
    const int arow = (wr * 64 + r15) * 128;
    const int brow = (wc * 64 + r15) * 128;
    const int g4 = lane >> 4, l7 = lane & 7;
    const int s0 = ((g4) ^ l7) * 16;
    const int s1 = ((4 + g4) ^ l7) * 16;

    const int nt = klen >> 6;

#define STAGE8(tk, buf) do { \
    GLDS16(Ag0 + (tk), As + (buf) * 16384 + 0 * 4096 + lw); \
    GLDS16(Ag1 + (tk), As + (buf) * 16384 + 1 * 4096 + lw); \
    GLDS16(Ag2 + (tk), As + (buf) * 16384 + 2 * 4096 + lw); \
    GLDS16(Ag3 + (tk), As + (buf) * 16384 + 3 * 4096 + lw); \
    GLDS16(Bg0 + (tk), Bs + (buf) * 8192 + 0 * 4096 + lw); \
    GLDS16(Bg1 + (tk), Bs + (buf) * 8192 + 1 * 4096 + lw); \
} while (0)

    // prologue: stage tiles 0,1 (12 loads/thread outstanding)
    STAGE8(0, 0);
    if (nt > 1) STAGE8(64, 1);

    int bcur = 0;   // buffer of tile t (= t % 3)
    for (int t = 0; t < nt - 1; ++t) {
        // own tile-t loads landed (t+1's 6 stay in flight) -> barrier ->
        // tile t fully staged block-wide
        asm volatile("s_waitcnt vmcnt(6)" ::: "memory");
        __builtin_amdgcn_s_barrier();
        if (t + 2 < nt) {
            int bn = bcur ? bcur - 1 : 2;        // (t+2) % 3
            STAGE8((t + 2) << 6, bn);
        }
        __builtin_amdgcn_s_setprio(1);
        mma_tile8(As + bcur * 16384, Bs + bcur * 8192, arow, brow, s0, s1, acc);
        __builtin_amdgcn_s_setprio(0);
        bcur = (bcur + 1 == 3) ? 0 : bcur + 1;
    }
    // epilogue: last tile
    asm volatile("s_waitcnt vmcnt(0)" ::: "memory");
    __builtin_amdgcn_s_barrier();
    __builtin_amdgcn_s_setprio(1);
    mma_tile8(As + bcur * 16384, Bs + bcur * 8192, arow, brow, s0, s1, acc);
    __builtin_amdgcn_s_setprio(0);
    // WAR fence for the NEXT segment's staging into these buffers
    asm volatile("s_waitcnt lgkmcnt(0)" ::: "memory");
    __builtin_amdgcn_s_barrier();
#undef STAGE8
}

// ---------------- epilogues (formulas valid for both 4-wave and 8-wave grids)
__device__ __forceinline__ void epi_out(
    f32x4 (&acc)[4][4], float* __restrict__ out, int rb, int cb)
{
    int lane = threadIdx.x & 63, wid = threadIdx.x >> 6;
    int wr = wid >> 1, wc = wid & 1, r15 = lane & 15;
    #pragma unroll
    for (int mi = 0; mi < 4; ++mi) {
        int row0 = rb + wr * 64 + mi * 16 + (lane >> 4) * 4;
        #pragma unroll
        for (int ni = 0; ni < 4; ++ni) {
            int col = cb + wc * 64 + ni * 16 + r15;
            #pragma unroll
            for (int r = 0; r < 4; ++r)
                out[(size_t)(row0 + r) * D_ + col] = acc[mi][ni][r];
        }
    }
}

__device__ __forceinline__ void epi_delta(
    f32x4 (&acc)[4][4], const float* __restrict__ V,
    const float* __restrict__ knorm, u16* __restrict__ deltaT,
    int rb, int cb)
{
    int lane = threadIdx.x & 63, wid = threadIdx.x >> 6;
    int wr = wid >> 1, wc = wid & 1, r15 = lane & 15;
    #pragma unroll
    for (int mi = 0; mi < 4; ++mi) {
        int row0 = rb + wr * 64 + mi * 16 + (lane >> 4) * 4;
        float inv[4];
        #pragma unroll
        for (int r = 0; r < 4; ++r) inv[r] = 1.0f / fmaxf(knorm[row0 + r], EPS);
        #pragma unroll
        for (int ni = 0; ni < 4; ++ni) {
            int col = cb + wc * 64 + ni * 16 + r15;
            float dv[4];
            #pragma unroll
            for (int r = 0; r < 4; ++r)
                dv[r] = V[(size_t)(row0 + r) * D_ + col] - acc[mi][ni][r] * inv[r];
            uint2 pv;
            pv.x = (unsigned)f2b(dv[0]) | ((unsigned)f2b(dv[1]) << 16);
            pv.y = (unsigned)f2b(dv[2]) | ((unsigned)f2b(dv[3]) << 16);
            *(uint2*)(deltaT + (size_t)col * N_ + row0) = pv;  // lanes 0/16/32/48 coalesce
        }
    }
}

// ---------------- FUSED retrieve + delta, 256x128 tiles, 512 blocks @ 1 block/CU.
// Blocks [0,256): retrieve (4 K-segments with ratio-plane folding = 64 BK64
// steps). Blocks [256,512): delta (16 steps). Retrieve-first -> each CU runs
// one retrieve then one delta = 80 steps (ideal makespan). bx = hw&7 keeps
// one MemT panel per XCD.
__global__ __launch_bounds__(512, 1) void g34_fused(
    const u16* __restrict__ sQ, const u16* __restrict__ MemT,
    const u16* __restrict__ sk, const float* __restrict__ V,
    const float* __restrict__ knorm, const float* __restrict__ ratT,
    float* __restrict__ out, u16* __restrict__ deltaT)
{
    __shared__ u16 As[3 * 16384];   // 96 KB
    __shared__ u16 Bs[3 * 8192];    // 48 KB
    int hw = blockIdx.x;
    int lane = threadIdx.x & 63, wid = threadIdx.x >> 6;
    int wr = wid >> 1;
    f32x4 acc[4][4];
    #pragma unroll
    for (int i = 0; i < 4; ++i)
        #pragma unroll
        for (int j = 0; j < 4; ++j) {
            f32x4 zz = {0.0f, 0.0f, 0.0f, 0.0f};
            acc[i][j] = zz;
        }
    if (hw < 256) {
        int bx = hw & 7, by = hw >> 3;
        int rb = by * 256, cb = bx * 128;
        #pragma unroll 1
        for (int m = 0; m < M_; ++m) {
            gemm_seg8p(As, Bs, sQ, D_, 0, MemT, M_ * D_, m * D_, rb, cb, D_, acc);
            const float* rp = ratT + (size_t)m * N_;
            #pragma unroll
            for (int mi = 0; mi < 4; ++mi) {
                int row0 = rb + wr * 64 + mi * 16 + (lane >> 4) * 4;
                float4 rt = *(const float4*)(rp + row0);
                #pragma unroll
                for (int ni = 0; ni < 4; ++ni) {
                    acc[mi][ni][0] *= rt.x; acc[mi][ni][1] *= rt.y;
                    acc[mi][ni][2] *= rt.z; acc[mi][ni][3] *= rt.w;
                }
            }
        }
        epi_out(acc, out, rb, cb);
    } else {
        int d = hw - 256;
        int bx = d & 7, by = d >> 3;
        int rb = by * 256, cb = bx * 128;
        gemm_seg8p(As, Bs, sk, D_, 0, MemT, M_ * D_, 0, rb, cb, D_, acc);
        epi_delta(acc, V, knorm, deltaT, rb, cb);
    }
}

// ---------------- update: out_mem(D,D) += (skT * deltaT^T)/N, split-K=8, fp32 atomics
#define KSPLIT 8
__global__ __launch_bounds__(256, 4) void g5_update(
    const u16* __restrict__ skT, const u16* __restrict__ deltaT,
    float* __restrict__ memout)
{
    __shared__ u16 As[2 * 4096];
    __shared__ u16 Bs[2 * 4096];
    f32x4 acc[4][4];
    #pragma unroll
    for (int i = 0; i < 4; ++i)
        #pragma unroll
        for (int j = 0; j < 4; ++j) {
            f32x4 zz = {0.0f, 0.0f, 0.0f, 0.0f};
            acc[i][j] = zz;
        }
    int rb = blockIdx.y * 128, cb = blockIdx.x * 128;
    int k0 = blockIdx.z * (N_ / KSPLIT);
    gemm_seg(As, Bs, skT, N_, k0, deltaT, N_, k0, rb, cb, N_ / KSPLIT, acc);
    int lane = threadIdx.x & 63, wid = threadIdx.x >> 6;
    int wr = wid >> 1, wc = wid & 1, r15 = lane & 15;
    const float sc = 1.0f / (float)N_;
    #pragma unroll
    for (int mi = 0; mi < 4; ++mi) {
        int row0 = rb + wr * 64 + mi * 16 + (lane >> 4) * 4;
        #pragma unroll
        for (int ni = 0; ni < 4; ++ni) {
            int col = cb + wc * 64 + ni * 16 + r15;
            #pragma unroll
            for (int r = 0; r < 4; ++r)
                atomicAdd(memout + (size_t)(row0 + r) * D_ + col, acc[mi][ni][r] * sc);
        }
    }
}

extern "C" void kernel_launch(void* const* d_in, const int* in_sizes, int n_in,
                              void* d_out, int out_size, void* d_ws, size_t ws_size,
                              hipStream_t stream) {
    const float* Q     = (const float*)d_in[0];
    const float* K     = (const float*)d_in[1];
    const float* V     = (const float*)d_in[2];
    const float* Mem   = (const float*)d_in[3];
    const float* Mnorm = (const float*)d_in[4];

    float* out      = (float*)d_out;
    float* out_mem  = out + (size_t)N_ * D_;        // D*D
    float* out_norm = out_mem + (size_t)D_ * D_;    // D

    // ---- workspace layout (needs ~74MB; ws >= 121MB proven in prior rounds) ----
    // [0,1MB):   fp32 stats: qnorm(M*N) knorm(N) colsum(D) weights(8) ratT(4*N)
    // [1,9MB):   MemT  bf16 [1024][4096]
    // [9,25MB):  sk    bf16 [8192][1024]
    // [25,41MB): skT   bf16 [1024][8192]
    // [41,57MB): sQ    bf16 [8192][1024]
    // [57,73MB): deltaT bf16 [1024][8192]
    char* wsb = (char*)d_ws;
    float* qnorm   = (float*)wsb;                   // 32768
    float* knorm   = qnorm + (size_t)M_ * N_;       // 8192
    float* colsum  = knorm + N_;                    // 1024
    float* weights = colsum + D_;                   // 8
    float* ratT    = weights + M_ * B_;             // 4*N = 32768 (16B aligned)
    u16* MemT   = (u16*)(wsb + (size_t)1  * (1 << 20));
    u16* sk     = (u16*)(wsb + (size_t)9  * (1 << 20));
    u16* skT    = (u16*)(wsb + (size_t)25 * (1 << 20));
    u16* sQ     = (u16*)(wsb + (size_t)41 * (1 << 20));
    u16* deltaT = (u16*)(wsb + (size_t)57 * (1 << 20));

    hipLaunchKernelGGL(k1_stats, dim3(N_), dim3(256), 0, stream, Q, Mnorm, qnorm, sQ, knorm, colsum);
    hipLaunchKernelGGL(prep_k, dim3(128, 16), dim3(256), 0, stream, K, Mnorm, sk, skT, colsum, knorm);
    hipLaunchKernelGGL(prep_memT, dim3(16, 16, 4), dim3(256), 0, stream, Mem, MemT, out_mem);
    hipLaunchKernelGGL(k2_weights, dim3(1), dim3(512), 0, stream, Mnorm, qnorm, weights);
    hipLaunchKernelGGL(k2_cvec, dim3(32), dim3(256), 0, stream, qnorm, weights, Mnorm, colsum, ratT, out_norm);
    hipLaunchKernelGGL(g34_fused, dim3(512), dim3(512), 0, stream,
                       sQ, MemT, sk, V, knorm, ratT, out, deltaT);
    hipLaunchKernelGGL(g5_update, dim3(8, 8, KSPLIT), dim3(256), 0, stream, skT, deltaT, out_mem);
}